// Round 19
// baseline (95.232 us; speedup 1.0000x reference)
//
#include <hip/hip_runtime.h>
#include <hip/hip_bf16.h>

#define NPIX 65536
#define NRAYS 65536
#define SS 48
#define NC 256
#define ND 16

typedef __attribute__((ext_vector_type(8))) short short8;
typedef __attribute__((ext_vector_type(4))) float f32x4;

__device__ __forceinline__ unsigned short f2bf(float x) {
    unsigned u = __float_as_uint(x);
    unsigned r = u + 0x7fff + ((u >> 16) & 1);
    return (unsigned short)(r >> 16);
}
__device__ __forceinline__ float bf2f(unsigned short h) {
    return __uint_as_float(((unsigned)h) << 16);
}

// ---------------- kFront: blocks [0,256) = pixel pass A (1 px/thread);
// blocks [256, 256+16384) = distortion, one wave per ray (shuffle scan).
// Block 0 additionally zeroes the accumulators used by later nodes.
__global__ __launch_bounds__(256) void kFront(
    const float* __restrict__ rgb_pred, const float* __restrict__ rgb_gt,
    const float* __restrict__ opacity, const int* __restrict__ sam,
    const float* __restrict__ semantic,
    const float* __restrict__ wsv, const float* __restrict__ deltas,
    const float* __restrict__ tsv, const int* __restrict__ rays_a,
    float* __restrict__ o_rgb, float* __restrict__ o_opac,
    float* __restrict__ o_dist,
    float* __restrict__ cntpart, float* __restrict__ usumpart,
    float* __restrict__ normpart, float* __restrict__ wsumpart,
    float* __restrict__ dev, float* __restrict__ scal,
    unsigned* __restrict__ doneC)
{
    __shared__ float cnt_s[NC];
    __shared__ float us_s[NC*17];
    __shared__ float red_s[8];
    const int t = threadIdx.x;
    const int lane = t & 63;
    const int w = t >> 6;

    if ((int)blockIdx.x < 256) {
        const int b = blockIdx.x;
        if (b == 0) {                      // zero next-stage accumulators
            dev[t] = 0.f;
            if (t == 0) {
                scal[2] = 0.f;
                ((unsigned*)scal)[3] = 0u;   // kD done counter
                *doneC = 0u;                 // kCP2 done counter
            }
        }
        for (int j = t; j < NC; j += 256) cnt_s[j] = 0.f;
        for (int j = t; j < NC*17; j += 256) us_s[j] = 0.f;
        __syncthreads();
        float nloc = 0.f, wloc = 0.f;
        {
            const int i = b*256 + t;
            const float pr0 = rgb_pred[3*i+0], pr1 = rgb_pred[3*i+1], pr2 = rgb_pred[3*i+2];
            const float g0 = rgb_gt[3*i+0],  g1 = rgb_gt[3*i+1],  g2 = rgb_gt[3*i+2];
            const float d0 = pr0-g0, d1 = pr1-g1, d2 = pr2-g2;
            o_rgb[3*i+0] = d0*d0; o_rgb[3*i+1] = d1*d1; o_rgb[3*i+2] = d2*d2;
            const float o = opacity[i] + 1e-10f;
            o_opac[i] = -0.001f * o * logf(o);
            const float4* sp = (const float4*)(semantic + (size_t)i*ND);
            const float4 a0 = sp[0], a1 = sp[1], a2 = sp[2], a3 = sp[3];
            const int seg = sam[i];
            if (seg > 0) {
                const int cl = seg - 1;
                const float ss =
                    a0.x*a0.x + a0.y*a0.y + a0.z*a0.z + a0.w*a0.w +
                    a1.x*a1.x + a1.y*a1.y + a1.z*a1.z + a1.w*a1.w +
                    a2.x*a2.x + a2.y*a2.y + a2.z*a2.z + a2.w*a2.w +
                    a3.x*a3.x + a3.y*a3.y + a3.z*a3.z + a3.w*a3.w;
                const float dn = sqrtf(ss) - 1.f;
                nloc += dn*dn; wloc += 1.f;
                atomicAdd(&cnt_s[cl], 1.f);
                float* up = us_s + cl*17;
                atomicAdd(up+0,  a0.x); atomicAdd(up+1,  a0.y);
                atomicAdd(up+2,  a0.z); atomicAdd(up+3,  a0.w);
                atomicAdd(up+4,  a1.x); atomicAdd(up+5,  a1.y);
                atomicAdd(up+6,  a1.z); atomicAdd(up+7,  a1.w);
                atomicAdd(up+8,  a2.x); atomicAdd(up+9,  a2.y);
                atomicAdd(up+10, a2.z); atomicAdd(up+11, a2.w);
                atomicAdd(up+12, a3.x); atomicAdd(up+13, a3.y);
                atomicAdd(up+14, a3.z); atomicAdd(up+15, a3.w);
            }
        }
        __syncthreads();
        for (int j = t; j < NC; j += 256) cntpart[b*NC + j] = cnt_s[j];
        for (int j = t; j < NC*ND; j += 256) {
            const int c = j >> 4, k = j & 15;
            usumpart[(size_t)b*NC*ND + j] = us_s[c*17 + k];
        }
#pragma unroll
        for (int off = 32; off > 0; off >>= 1) {
            nloc += __shfl_xor(nloc, off);
            wloc += __shfl_xor(wloc, off);
        }
        if (lane == 0) { red_s[w] = nloc; red_s[4 + w] = wloc; }
        __syncthreads();
        if (t == 0) {
            normpart[b] = red_s[0]+red_s[1]+red_s[2]+red_s[3];
            wsumpart[b] = red_s[4]+red_s[5]+red_s[6]+red_s[7];
        }
    } else {
        // distortion: one wave per ray
        const int ray = (blockIdx.x - 256)*4 + w;
        const int start = rays_a[3*ray + 1];
        const int cnt   = rays_a[3*ray + 2];
        const bool act = lane < cnt;
        const float w_ = act ? wsv[start+lane]    : 0.f;
        const float t_ = act ? tsv[start+lane]    : 0.f;
        const float d_ = act ? deltas[start+lane] : 0.f;
        const float wt_ = w_*t_;
        float sw = w_, swt = wt_;
#pragma unroll
        for (int off = 1; off < 64; off <<= 1) {
            const float aw  = __shfl_up(sw, off);
            const float awt = __shfl_up(swt, off);
            if (lane >= off) { sw += aw; swt += awt; }
        }
        const float Wex = sw - w_, WTex = swt - wt_;
        float per = 2.f*w_*(t_*Wex - WTex) + w_*w_*d_*(1.f/3.f);
#pragma unroll
        for (int off = 32; off > 0; off >>= 1) per += __shfl_xor(per, off);
        if (lane == 0) o_dist[ray] = 0.001f * per;
    }
}

// ---------------- kP1: per-class block reduce -> cnt, u; block 0 also norm/wsum ----------------
__global__ __launch_bounds__(256) void kP1(
    const float* __restrict__ cntpart, const float* __restrict__ usumpart,
    const float* __restrict__ normpart, const float* __restrict__ wsumpart,
    float* __restrict__ cnt, float* __restrict__ u,
    float* __restrict__ scal)
{
    const int c = blockIdx.x;
    const int t = threadIdx.x;
    const int kk = t & 15;
    const int s  = t >> 4;

    float us = 0.f;
    for (int b = s; b < 256; b += 16)
        us += usumpart[(size_t)b*(NC*ND) + c*ND + kk];

    __shared__ float lds[16][17];
    lds[s][kk] = us;

    float cs = cntpart[t*NC + c];
#pragma unroll
    for (int off = 32; off > 0; off >>= 1) cs += __shfl_xor(cs, off);
    __shared__ float cred[4];
    if ((t & 63) == 0) cred[t >> 6] = cs;
    __syncthreads();

    if (t < 16) {
        const float ctot = cred[0]+cred[1]+cred[2]+cred[3];
        float tot = 0.f;
#pragma unroll
        for (int s2 = 0; s2 < 16; ++s2) tot += lds[s2][t];
        u[c*ND + t] = tot / fmaxf(ctot, 1.f);
        if (t == 0) cnt[c] = ctot;
    }

    if (c == 0) {
        float n  = normpart[t];
        float w2 = wsumpart[t];
#pragma unroll
        for (int off = 32; off > 0; off >>= 1) {
            n  += __shfl_xor(n, off);
            w2 += __shfl_xor(w2, off);
        }
        __shared__ float nr[4], wr[4];
        if ((t & 63) == 0) { nr[t >> 6] = n; wr[t >> 6] = w2; }
        __syncthreads();
        if (t == 0) {
            scal[0] = nr[0]+nr[1]+nr[2]+nr[3];
            scal[1] = wr[0]+wr[1]+wr[2]+wr[3];
        }
    }
}

// ---------------- kCP2: dev via GLOBAL atomics; last block computes phi/uphi/mask ----------------
__global__ __launch_bounds__(256) void kCP2(
    const float* __restrict__ semantic, const int* __restrict__ sam,
    const float* __restrict__ u, const float* __restrict__ cnt,
    float* __restrict__ dev, float* __restrict__ uphi,
    unsigned short* __restrict__ uphi_h, unsigned short* __restrict__ uphi_l,
    float* __restrict__ mf, unsigned* __restrict__ doneC)
{
    __shared__ float u_s[NC*20];
    __shared__ int lastflag;
    const int t = threadIdx.x, b = blockIdx.x;
    for (int j = t; j < NC*ND; j += 256) {
        const int c = j >> 4, k = j & 15;
        u_s[c*20 + k] = u[j];
    }
    __syncthreads();
    {
        const int i = b*256 + t;
        const int seg = sam[i];
        if (seg > 0) {
            const int cl = seg - 1;
            const float4* sp = (const float4*)(semantic + (size_t)i*ND);
            const float4 a0 = sp[0], a1 = sp[1], a2 = sp[2], a3 = sp[3];
            const float4* up = (const float4*)(u_s + cl*20);
            const float4 u0 = up[0], u1 = up[1], u2 = up[2], u3 = up[3];
            float q, d2 = 0.f;
            q = a0.x-u0.x; d2 += q*q;  q = a0.y-u0.y; d2 += q*q;
            q = a0.z-u0.z; d2 += q*q;  q = a0.w-u0.w; d2 += q*q;
            q = a1.x-u1.x; d2 += q*q;  q = a1.y-u1.y; d2 += q*q;
            q = a1.z-u1.z; d2 += q*q;  q = a1.w-u1.w; d2 += q*q;
            q = a2.x-u2.x; d2 += q*q;  q = a2.y-u2.y; d2 += q*q;
            q = a2.z-u2.z; d2 += q*q;  q = a2.w-u2.w; d2 += q*q;
            q = a3.x-u3.x; d2 += q*q;  q = a3.y-u3.y; d2 += q*q;
            q = a3.z-u3.z; d2 += q*q;  q = a3.w-u3.w; d2 += q*q;
            atomicAdd(&dev[cl], sqrtf(d2));
        }
    }
    __syncthreads();               // all threads' atomics executed
    if (t == 0) {
        __threadfence();
        const unsigned old = atomicAdd(doneC, 1u);
        lastflag = (old == 255u) ? 1 : 0;
    }
    __syncthreads();
    if (lastflag) {                // LAST block: kP2's work, one class per thread
        const int c = t;
        const float dv = atomicAdd(&dev[c], 0.f);      // coherent read
        const float cs = cnt[c];
        const float csafe = fmaxf(cs, 1.f);
        const float phiraw = dv / (csafe * logf(cs + 10.f));
        const float phi = fminf(fmaxf(phiraw * 10.f, 0.1f), 1.f);
        const float inv = 1.f / phi;
        mf[c] = (cs > 2.0f) ? 1.f : 0.f;
#pragma unroll
        for (int k = 0; k < ND; ++k) {
            const float v = u_s[c*20 + k] * inv;
            uphi[c*ND + k] = v;
            const unsigned short h = f2bf(v);
            uphi_h[c*ND + k] = h;
            uphi_l[c*ND + k] = f2bf(v - bf2f(h));
        }
    }
}

// ---------------- kD: NCE via MFMA (R11-exact: bf16 hi/lo split, K=32 packing) ----------------
__global__ __launch_bounds__(256, 1) void kD(
    const float* __restrict__ semantic, const int* __restrict__ sam,
    const float* __restrict__ uphi,
    const unsigned short* __restrict__ uphi_h, const unsigned short* __restrict__ uphi_l,
    const float* __restrict__ mf,
    float* __restrict__ scal, float* __restrict__ o_sem)
{
    __shared__ float dlds[4][64];
    __shared__ float red_s[4];
    const int t = threadIdx.x;
    const int lane = t & 63;
    const int w = t >> 6;
    const int col = lane & 15;
    const int g   = lane >> 4;
    const int wbase = blockIdx.x * 256 + w * 64;

    short8 A[4];
#pragma unroll
    for (int pt = 0; pt < 4; ++pt) {
        const float* sp = semantic + (size_t)(wbase + pt*16 + col)*ND + (g & 1)*8;
        const float4 f0 = ((const float4*)sp)[0];
        const float4 f1 = ((const float4*)sp)[1];
        float fv[8] = {f0.x,f0.y,f0.z,f0.w, f1.x,f1.y,f1.z,f1.w};
        short8 a;
#pragma unroll
        for (int i = 0; i < 8; ++i) {
            const unsigned short h = f2bf(fv[i]);
            const unsigned short l = f2bf(fv[i] - bf2f(h));
            a[i] = (short)((g < 2) ? h : l);
        }
        A[pt] = a;
    }

    short8 B1[16], B2[16];
    const short8* Bh = (const short8*)uphi_h;
    const short8* Bl = (const short8*)uphi_l;
    const short8 zero8 = {0,0,0,0,0,0,0,0};
#pragma unroll
    for (int ct = 0; ct < 16; ++ct) {
        const int cls = ct*16 + col;
        const int idx = cls*2 + (g & 1);
        B1[ct] = Bh[idx];
        B2[ct] = (g < 2) ? Bl[idx] : zero8;
    }

    float mfv[16];
#pragma unroll
    for (int ct = 0; ct < 16; ++ct) mfv[ct] = mf[ct*16 + col];

    float dacc[4][4] = {};
#pragma unroll
    for (int ct = 0; ct < 16; ++ct) {
#pragma unroll
        for (int pt = 0; pt < 4; ++pt) {
            f32x4 d = {0.f, 0.f, 0.f, 0.f};
            d = __builtin_amdgcn_mfma_f32_16x16x32_bf16(A[pt], B2[ct], d, 0, 0, 0);
            d = __builtin_amdgcn_mfma_f32_16x16x32_bf16(A[pt], B1[ct], d, 0, 0, 0);
#pragma unroll
            for (int r = 0; r < 4; ++r)
                dacc[pt][r] += mfv[ct] * __expf(d[r]);
        }
    }

#pragma unroll
    for (int pt = 0; pt < 4; ++pt)
#pragma unroll
        for (int r = 0; r < 4; ++r) {
            float v = dacc[pt][r];
            v += __shfl_xor(v, 1);
            v += __shfl_xor(v, 2);
            v += __shfl_xor(v, 4);
            v += __shfl_xor(v, 8);
            dacc[pt][r] = v;
        }

    if (col == 0) {
#pragma unroll
        for (int pt = 0; pt < 4; ++pt)
#pragma unroll
            for (int r = 0; r < 4; ++r)
                dlds[w][pt*16 + 4*g + r] = dacc[pt][r];
    }
    const float denom = dlds[w][lane] + 1e-6f;

    const int p = wbase + lane;
    const int seg = sam[p];
    const int cl = (seg > 0) ? (seg - 1) : 0;
    const float4* sp = (const float4*)(semantic + (size_t)p*ND);
    const float4 b0 = sp[0], b1 = sp[1], b2 = sp[2], b3 = sp[3];
    const float4* uo = (const float4*)(uphi + cl*ND);
    const float4 c0 = uo[0], c1 = uo[1], c2 = uo[2], c3 = uo[3];
    const float down =
        b0.x*c0.x + b0.y*c0.y + b0.z*c0.z + b0.w*c0.w +
        b1.x*c1.x + b1.y*c1.y + b1.z*c1.z + b1.w*c1.w +
        b2.x*c2.x + b2.y*c2.y + b2.z*c2.z + b2.w*c2.w +
        b3.x*c3.x + b3.y*c3.y + b3.z*c3.z + b3.w*c3.w;
    const float mo = mf[cl];
    float contrib = (seg > 0 && mo > 0.5f) ? (__logf(denom) - down) : 0.f;

#pragma unroll
    for (int off = 32; off > 0; off >>= 1) contrib += __shfl_xor(contrib, off);
    if ((t & 63) == 0) red_s[t >> 6] = contrib;
    __syncthreads();
    if (t == 0) atomicAdd(&scal[2], red_s[0]+red_s[1]+red_s[2]+red_s[3]);

    if (t == 0) {
        __threadfence();
        unsigned* done = (unsigned*)(scal + 3);
        const unsigned old = atomicAdd(done, 1u);
        if (old == gridDim.x - 1) {
            const float proto = atomicAdd(&scal[2], 0.f);
            const float nrm   = scal[0];
            const float wsum  = scal[1];
            o_sem[0] = 1e-4f * proto + 100.f * nrm / fmaxf(wsum, 1.f);
        }
    }
}

extern "C" void kernel_launch(void* const* d_in, const int* in_sizes, int n_in,
                              void* d_out, int out_size, void* d_ws, size_t ws_size,
                              hipStream_t stream)
{
    const float* rgb_pred = (const float*)d_in[0];
    const float* rgb_gt   = (const float*)d_in[1];
    const float* opacity  = (const float*)d_in[2];
    const float* wsv      = (const float*)d_in[3];
    const float* deltas   = (const float*)d_in[4];
    const float* tsv      = (const float*)d_in[5];
    const int*   rays_a   = (const int*)d_in[6];
    const int*   sam      = (const int*)d_in[7];
    const float* semantic = (const float*)d_in[8];

    float* out    = (float*)d_out;
    float* o_rgb  = out;                 // 196608
    float* o_opac = out + 196608;        // 65536
    float* o_dist = out + 262144;        // 65536
    float* o_sem  = out + 327680;        // 1
    float* wsf    = (float*)d_ws;

    float*          w_cntpart  = wsf;                                  // 256*NC
    float*          w_usum     = w_cntpart + (size_t)256*NC;           // 256*NC*ND
    float*          w_dev      = w_usum + (size_t)256*NC*ND;           // NC
    float*          w_cnt      = w_dev + NC;                           // NC
    float*          w_u        = w_cnt + NC;                           // NC*ND
    float*          w_uphi     = w_u + NC*ND;                          // NC*ND
    float*          w_scal     = w_uphi + NC*ND;                       // 8: [0]norm [1]wsum [2]proto [3]doneD
    float*          w_mf       = w_scal + 8;                           // NC
    float*          w_normpart = w_mf + NC;                            // 256
    float*          w_wsumpart = w_normpart + 256;                     // 256
    unsigned*       w_doneC    = (unsigned*)(w_wsumpart + 256);        // 1 (+pad)
    unsigned short* w_uh       = (unsigned short*)(w_doneC + 4);       // NC*ND
    unsigned short* w_ul       = w_uh + NC*ND;                         // NC*ND

    kFront<<<256 + NRAYS/4, 256, 0, stream>>>(
        rgb_pred, rgb_gt, opacity, sam, semantic,
        wsv, deltas, tsv, rays_a,
        o_rgb, o_opac, o_dist,
        w_cntpart, w_usum, w_normpart, w_wsumpart,
        w_dev, w_scal, w_doneC);
    kP1<<<NC, 256, 0, stream>>>(w_cntpart, w_usum, w_normpart, w_wsumpart,
                                w_cnt, w_u, w_scal);
    kCP2<<<NC, 256, 0, stream>>>(semantic, sam, w_u, w_cnt,
                                 w_dev, w_uphi, w_uh, w_ul, w_mf, w_doneC);
    kD<<<NPIX/256, 256, 0, stream>>>(semantic, sam, w_uphi, w_uh, w_ul,
                                     w_mf, w_scal, o_sem);
}

// Round 20
// 69.424 us; speedup vs baseline: 1.3717x; 1.3717x over previous
//
#include <hip/hip_runtime.h>
#include <hip/hip_bf16.h>

#define NPIX 65536
#define NRAYS 65536
#define SS 48
#define NC 256
#define ND 16

typedef __attribute__((ext_vector_type(8))) short short8;
typedef __attribute__((ext_vector_type(4))) float f32x4;

__device__ __forceinline__ unsigned short f2bf(float x) {
    unsigned u = __float_as_uint(x);
    unsigned r = u + 0x7fff + ((u >> 16) & 1);
    return (unsigned short)(r >> 16);
}
__device__ __forceinline__ float bf2f(unsigned short h) {
    return __uint_as_float(((unsigned)h) << 16);
}

// ---------------- kFront: blocks [0,256) = pixel pass A (1 px/thread);
// blocks [256, 256+16384) = distortion, one wave per ray (shuffle scan).
// Block 0 zeroes dev/scal[2]/done counters (visible to later kernels).
__global__ __launch_bounds__(256) void kFront(
    const float* __restrict__ rgb_pred, const float* __restrict__ rgb_gt,
    const float* __restrict__ opacity, const int* __restrict__ sam,
    const float* __restrict__ semantic,
    const float* __restrict__ wsv, const float* __restrict__ deltas,
    const float* __restrict__ tsv, const int* __restrict__ rays_a,
    float* __restrict__ o_rgb, float* __restrict__ o_opac,
    float* __restrict__ o_dist,
    float* __restrict__ cntpart, float* __restrict__ usumpart,
    float* __restrict__ normpart, float* __restrict__ wsumpart,
    float* __restrict__ dev, float* __restrict__ scal,
    unsigned* __restrict__ doneC)
{
    __shared__ float cnt_s[NC];
    __shared__ float us_s[NC*17];
    __shared__ float red_s[8];
    const int t = threadIdx.x;
    const int lane = t & 63;
    const int w = t >> 6;

    if ((int)blockIdx.x < 256) {
        const int b = blockIdx.x;
        if (b == 0) {
            dev[t] = 0.f;
            if (t == 0) {
                scal[2] = 0.f;
                ((unsigned*)scal)[3] = 0u;   // kD done counter
                *doneC = 0u;                 // kCdev done counter
            }
        }
        for (int j = t; j < NC; j += 256) cnt_s[j] = 0.f;
        for (int j = t; j < NC*17; j += 256) us_s[j] = 0.f;
        __syncthreads();
        float nloc = 0.f, wloc = 0.f;
        {
            const int i = b*256 + t;
            const float pr0 = rgb_pred[3*i+0], pr1 = rgb_pred[3*i+1], pr2 = rgb_pred[3*i+2];
            const float g0 = rgb_gt[3*i+0],  g1 = rgb_gt[3*i+1],  g2 = rgb_gt[3*i+2];
            const float d0 = pr0-g0, d1 = pr1-g1, d2 = pr2-g2;
            o_rgb[3*i+0] = d0*d0; o_rgb[3*i+1] = d1*d1; o_rgb[3*i+2] = d2*d2;
            const float o = opacity[i] + 1e-10f;
            o_opac[i] = -0.001f * o * logf(o);
            const float4* sp = (const float4*)(semantic + (size_t)i*ND);
            const float4 a0 = sp[0], a1 = sp[1], a2 = sp[2], a3 = sp[3];
            const int seg = sam[i];
            if (seg > 0) {
                const int cl = seg - 1;
                const float ss =
                    a0.x*a0.x + a0.y*a0.y + a0.z*a0.z + a0.w*a0.w +
                    a1.x*a1.x + a1.y*a1.y + a1.z*a1.z + a1.w*a1.w +
                    a2.x*a2.x + a2.y*a2.y + a2.z*a2.z + a2.w*a2.w +
                    a3.x*a3.x + a3.y*a3.y + a3.z*a3.z + a3.w*a3.w;
                const float dn = sqrtf(ss) - 1.f;
                nloc += dn*dn; wloc += 1.f;
                atomicAdd(&cnt_s[cl], 1.f);
                float* up = us_s + cl*17;
                atomicAdd(up+0,  a0.x); atomicAdd(up+1,  a0.y);
                atomicAdd(up+2,  a0.z); atomicAdd(up+3,  a0.w);
                atomicAdd(up+4,  a1.x); atomicAdd(up+5,  a1.y);
                atomicAdd(up+6,  a1.z); atomicAdd(up+7,  a1.w);
                atomicAdd(up+8,  a2.x); atomicAdd(up+9,  a2.y);
                atomicAdd(up+10, a2.z); atomicAdd(up+11, a2.w);
                atomicAdd(up+12, a3.x); atomicAdd(up+13, a3.y);
                atomicAdd(up+14, a3.z); atomicAdd(up+15, a3.w);
            }
        }
        __syncthreads();
        for (int j = t; j < NC; j += 256) cntpart[b*NC + j] = cnt_s[j];
        for (int j = t; j < NC*ND; j += 256) {
            const int c = j >> 4, k = j & 15;
            usumpart[(size_t)b*NC*ND + j] = us_s[c*17 + k];
        }
#pragma unroll
        for (int off = 32; off > 0; off >>= 1) {
            nloc += __shfl_xor(nloc, off);
            wloc += __shfl_xor(wloc, off);
        }
        if (lane == 0) { red_s[w] = nloc; red_s[4 + w] = wloc; }
        __syncthreads();
        if (t == 0) {
            normpart[b] = red_s[0]+red_s[1]+red_s[2]+red_s[3];
            wsumpart[b] = red_s[4]+red_s[5]+red_s[6]+red_s[7];
        }
    } else {
        // distortion: one wave per ray
        const int ray = (blockIdx.x - 256)*4 + w;
        const int start = rays_a[3*ray + 1];
        const int cnt   = rays_a[3*ray + 2];
        const bool act = lane < cnt;
        const float w_ = act ? wsv[start+lane]    : 0.f;
        const float t_ = act ? tsv[start+lane]    : 0.f;
        const float d_ = act ? deltas[start+lane] : 0.f;
        const float wt_ = w_*t_;
        float sw = w_, swt = wt_;
#pragma unroll
        for (int off = 1; off < 64; off <<= 1) {
            const float aw  = __shfl_up(sw, off);
            const float awt = __shfl_up(swt, off);
            if (lane >= off) { sw += aw; swt += awt; }
        }
        const float Wex = sw - w_, WTex = swt - wt_;
        float per = 2.f*w_*(t_*Wex - WTex) + w_*w_*d_*(1.f/3.f);
#pragma unroll
        for (int off = 32; off > 0; off >>= 1) per += __shfl_xor(per, off);
        if (lane == 0) o_dist[ray] = 0.001f * per;
    }
}

// ---------------- kP1: per-class block reduce -> cnt, u; block 0 also norm/wsum ----------------
__global__ __launch_bounds__(256) void kP1(
    const float* __restrict__ cntpart, const float* __restrict__ usumpart,
    const float* __restrict__ normpart, const float* __restrict__ wsumpart,
    float* __restrict__ cnt, float* __restrict__ u,
    float* __restrict__ scal)
{
    const int c = blockIdx.x;
    const int t = threadIdx.x;
    const int kk = t & 15;
    const int s  = t >> 4;

    float us = 0.f;
    for (int b = s; b < 256; b += 16)
        us += usumpart[(size_t)b*(NC*ND) + c*ND + kk];

    __shared__ float lds[16][17];
    lds[s][kk] = us;

    float cs = cntpart[t*NC + c];
#pragma unroll
    for (int off = 32; off > 0; off >>= 1) cs += __shfl_xor(cs, off);
    __shared__ float cred[4];
    if ((t & 63) == 0) cred[t >> 6] = cs;
    __syncthreads();

    if (t < 16) {
        const float ctot = cred[0]+cred[1]+cred[2]+cred[3];
        float tot = 0.f;
#pragma unroll
        for (int s2 = 0; s2 < 16; ++s2) tot += lds[s2][t];
        u[c*ND + t] = tot / fmaxf(ctot, 1.f);
        if (t == 0) cnt[c] = ctot;
    }

    if (c == 0) {
        float n  = normpart[t];
        float w2 = wsumpart[t];
#pragma unroll
        for (int off = 32; off > 0; off >>= 1) {
            n  += __shfl_xor(n, off);
            w2 += __shfl_xor(w2, off);
        }
        __shared__ float nr[4], wr[4];
        if ((t & 63) == 0) { nr[t >> 6] = n; wr[t >> 6] = w2; }
        __syncthreads();
        if (t == 0) {
            scal[0] = nr[0]+nr[1]+nr[2]+nr[3];
            scal[1] = wr[0]+wr[1]+wr[2]+wr[3];
        }
    }
}

// ---------------- kCdev: LDS dev aggregation -> 256 global atomics/block;
// last block (done-counter) computes phi/uphi/uh/ul/mf. ----------------
__global__ __launch_bounds__(256) void kCdev(
    const float* __restrict__ semantic, const int* __restrict__ sam,
    const float* __restrict__ u, const float* __restrict__ cnt,
    float* __restrict__ dev, float* __restrict__ uphi,
    unsigned short* __restrict__ uphi_h, unsigned short* __restrict__ uphi_l,
    float* __restrict__ mf, unsigned* __restrict__ doneC)
{
    __shared__ float u_s[NC*20];
    __shared__ float dev_s[NC];
    __shared__ int lastflag;
    const int t = threadIdx.x, b = blockIdx.x;
    for (int j = t; j < NC*ND; j += 256) {
        const int c = j >> 4, k = j & 15;
        u_s[c*20 + k] = u[j];
    }
    for (int j = t; j < NC; j += 256) dev_s[j] = 0.f;
    __syncthreads();
    {
        const int i = b*256 + t;
        const int seg = sam[i];
        if (seg > 0) {
            const int cl = seg - 1;
            const float4* sp = (const float4*)(semantic + (size_t)i*ND);
            const float4 a0 = sp[0], a1 = sp[1], a2 = sp[2], a3 = sp[3];
            const float4* up = (const float4*)(u_s + cl*20);
            const float4 u0 = up[0], u1 = up[1], u2 = up[2], u3 = up[3];
            float q, d2 = 0.f;
            q = a0.x-u0.x; d2 += q*q;  q = a0.y-u0.y; d2 += q*q;
            q = a0.z-u0.z; d2 += q*q;  q = a0.w-u0.w; d2 += q*q;
            q = a1.x-u1.x; d2 += q*q;  q = a1.y-u1.y; d2 += q*q;
            q = a1.z-u1.z; d2 += q*q;  q = a1.w-u1.w; d2 += q*q;
            q = a2.x-u2.x; d2 += q*q;  q = a2.y-u2.y; d2 += q*q;
            q = a2.z-u2.z; d2 += q*q;  q = a2.w-u2.w; d2 += q*q;
            q = a3.x-u3.x; d2 += q*q;  q = a3.y-u3.y; d2 += q*q;
            q = a3.z-u3.z; d2 += q*q;  q = a3.w-u3.w; d2 += q*q;
            atomicAdd(&dev_s[cl], sqrtf(d2));
        }
    }
    __syncthreads();
    // one global atomic per class per block (aggregated) — low contention
    if (dev_s[t] != 0.f) atomicAdd(&dev[t], dev_s[t]);
    __threadfence();
    __syncthreads();
    if (t == 0) {
        const unsigned old = atomicAdd(doneC, 1u);
        lastflag = (old == 255u) ? 1 : 0;
    }
    __syncthreads();
    if (lastflag) {                 // LAST block: kP2's work, one class per thread
        const int c = t;
        const float dv = atomicAdd(&dev[c], 0.f);      // device-coherent read
        const float cs = cnt[c];
        const float csafe = fmaxf(cs, 1.f);
        const float phiraw = dv / (csafe * logf(cs + 10.f));
        const float phi = fminf(fmaxf(phiraw * 10.f, 0.1f), 1.f);
        const float inv = 1.f / phi;
        mf[c] = (cs > 2.0f) ? 1.f : 0.f;
#pragma unroll
        for (int k = 0; k < ND; ++k) {
            const float v = u_s[c*20 + k] * inv;
            uphi[c*ND + k] = v;
            const unsigned short h = f2bf(v);
            uphi_h[c*ND + k] = h;
            uphi_l[c*ND + k] = f2bf(v - bf2f(h));
        }
    }
}

// ---------------- kD: NCE via MFMA (R11-exact: bf16 hi/lo split, K=32 packing) ----------------
__global__ __launch_bounds__(256, 1) void kD(
    const float* __restrict__ semantic, const int* __restrict__ sam,
    const float* __restrict__ uphi,
    const unsigned short* __restrict__ uphi_h, const unsigned short* __restrict__ uphi_l,
    const float* __restrict__ mf,
    float* __restrict__ scal, float* __restrict__ o_sem)
{
    __shared__ float dlds[4][64];
    __shared__ float red_s[4];
    const int t = threadIdx.x;
    const int lane = t & 63;
    const int w = t >> 6;
    const int col = lane & 15;
    const int g   = lane >> 4;
    const int wbase = blockIdx.x * 256 + w * 64;

    short8 A[4];
#pragma unroll
    for (int pt = 0; pt < 4; ++pt) {
        const float* sp = semantic + (size_t)(wbase + pt*16 + col)*ND + (g & 1)*8;
        const float4 f0 = ((const float4*)sp)[0];
        const float4 f1 = ((const float4*)sp)[1];
        float fv[8] = {f0.x,f0.y,f0.z,f0.w, f1.x,f1.y,f1.z,f1.w};
        short8 a;
#pragma unroll
        for (int i = 0; i < 8; ++i) {
            const unsigned short h = f2bf(fv[i]);
            const unsigned short l = f2bf(fv[i] - bf2f(h));
            a[i] = (short)((g < 2) ? h : l);
        }
        A[pt] = a;
    }

    short8 B1[16], B2[16];
    const short8* Bh = (const short8*)uphi_h;
    const short8* Bl = (const short8*)uphi_l;
    const short8 zero8 = {0,0,0,0,0,0,0,0};
#pragma unroll
    for (int ct = 0; ct < 16; ++ct) {
        const int cls = ct*16 + col;
        const int idx = cls*2 + (g & 1);
        B1[ct] = Bh[idx];
        B2[ct] = (g < 2) ? Bl[idx] : zero8;
    }

    float mfv[16];
#pragma unroll
    for (int ct = 0; ct < 16; ++ct) mfv[ct] = mf[ct*16 + col];

    float dacc[4][4] = {};
#pragma unroll
    for (int ct = 0; ct < 16; ++ct) {
#pragma unroll
        for (int pt = 0; pt < 4; ++pt) {
            f32x4 d = {0.f, 0.f, 0.f, 0.f};
            d = __builtin_amdgcn_mfma_f32_16x16x32_bf16(A[pt], B2[ct], d, 0, 0, 0);
            d = __builtin_amdgcn_mfma_f32_16x16x32_bf16(A[pt], B1[ct], d, 0, 0, 0);
#pragma unroll
            for (int r = 0; r < 4; ++r)
                dacc[pt][r] += mfv[ct] * __expf(d[r]);
        }
    }

#pragma unroll
    for (int pt = 0; pt < 4; ++pt)
#pragma unroll
        for (int r = 0; r < 4; ++r) {
            float v = dacc[pt][r];
            v += __shfl_xor(v, 1);
            v += __shfl_xor(v, 2);
            v += __shfl_xor(v, 4);
            v += __shfl_xor(v, 8);
            dacc[pt][r] = v;
        }

    if (col == 0) {
#pragma unroll
        for (int pt = 0; pt < 4; ++pt)
#pragma unroll
            for (int r = 0; r < 4; ++r)
                dlds[w][pt*16 + 4*g + r] = dacc[pt][r];
    }
    const float denom = dlds[w][lane] + 1e-6f;

    const int p = wbase + lane;
    const int seg = sam[p];
    const int cl = (seg > 0) ? (seg - 1) : 0;
    const float4* sp = (const float4*)(semantic + (size_t)p*ND);
    const float4 b0 = sp[0], b1 = sp[1], b2 = sp[2], b3 = sp[3];
    const float4* uo = (const float4*)(uphi + cl*ND);
    const float4 c0 = uo[0], c1 = uo[1], c2 = uo[2], c3 = uo[3];
    const float down =
        b0.x*c0.x + b0.y*c0.y + b0.z*c0.z + b0.w*c0.w +
        b1.x*c1.x + b1.y*c1.y + b1.z*c1.z + b1.w*c1.w +
        b2.x*c2.x + b2.y*c2.y + b2.z*c2.z + b2.w*c2.w +
        b3.x*c3.x + b3.y*c3.y + b3.z*c3.z + b3.w*c3.w;
    const float mo = mf[cl];
    float contrib = (seg > 0 && mo > 0.5f) ? (__logf(denom) - down) : 0.f;

#pragma unroll
    for (int off = 32; off > 0; off >>= 1) contrib += __shfl_xor(contrib, off);
    if ((t & 63) == 0) red_s[t >> 6] = contrib;
    __syncthreads();
    if (t == 0) atomicAdd(&scal[2], red_s[0]+red_s[1]+red_s[2]+red_s[3]);

    if (t == 0) {
        __threadfence();
        unsigned* done = (unsigned*)(scal + 3);
        const unsigned old = atomicAdd(done, 1u);
        if (old == gridDim.x - 1) {
            const float proto = atomicAdd(&scal[2], 0.f);
            const float nrm   = scal[0];
            const float wsum  = scal[1];
            o_sem[0] = 1e-4f * proto + 100.f * nrm / fmaxf(wsum, 1.f);
        }
    }
}

extern "C" void kernel_launch(void* const* d_in, const int* in_sizes, int n_in,
                              void* d_out, int out_size, void* d_ws, size_t ws_size,
                              hipStream_t stream)
{
    const float* rgb_pred = (const float*)d_in[0];
    const float* rgb_gt   = (const float*)d_in[1];
    const float* opacity  = (const float*)d_in[2];
    const float* wsv      = (const float*)d_in[3];
    const float* deltas   = (const float*)d_in[4];
    const float* tsv      = (const float*)d_in[5];
    const int*   rays_a   = (const int*)d_in[6];
    const int*   sam      = (const int*)d_in[7];
    const float* semantic = (const float*)d_in[8];

    float* out    = (float*)d_out;
    float* o_rgb  = out;                 // 196608
    float* o_opac = out + 196608;        // 65536
    float* o_dist = out + 262144;        // 65536
    float* o_sem  = out + 327680;        // 1
    float* wsf    = (float*)d_ws;

    float*          w_cntpart  = wsf;                                  // 256*NC
    float*          w_usum     = w_cntpart + (size_t)256*NC;           // 256*NC*ND
    float*          w_dev      = w_usum + (size_t)256*NC*ND;           // NC
    float*          w_cnt      = w_dev + NC;                           // NC
    float*          w_u        = w_cnt + NC;                           // NC*ND
    float*          w_uphi     = w_u + NC*ND;                          // NC*ND
    float*          w_scal     = w_uphi + NC*ND;                       // 8: [0]norm [1]wsum [2]proto [3]doneD
    float*          w_mf       = w_scal + 8;                           // NC
    float*          w_normpart = w_mf + NC;                            // 256
    float*          w_wsumpart = w_normpart + 256;                     // 256
    unsigned*       w_doneC    = (unsigned*)(w_wsumpart + 256);        // 1 (+pad)
    unsigned short* w_uh       = (unsigned short*)(w_doneC + 4);       // NC*ND
    unsigned short* w_ul       = w_uh + NC*ND;                         // NC*ND

    kFront<<<256 + NRAYS/4, 256, 0, stream>>>(
        rgb_pred, rgb_gt, opacity, sam, semantic,
        wsv, deltas, tsv, rays_a,
        o_rgb, o_opac, o_dist,
        w_cntpart, w_usum, w_normpart, w_wsumpart,
        w_dev, w_scal, w_doneC);
    kP1<<<NC, 256, 0, stream>>>(w_cntpart, w_usum, w_normpart, w_wsumpart,
                                w_cnt, w_u, w_scal);
    kCdev<<<NC, 256, 0, stream>>>(semantic, sam, w_u, w_cnt,
                                  w_dev, w_uphi, w_uh, w_ul, w_mf, w_doneC);
    kD<<<NPIX/256, 256, 0, stream>>>(semantic, sam, w_uphi, w_uh, w_ul,
                                     w_mf, w_scal, o_sem);
}